// Round 15
// baseline (181.224 us; speedup 1.0000x reference)
//
#include <hip/hip_runtime.h>
#include <hip/hip_bf16.h>
#include <math.h>

// Problem constants
#define B_  4
#define L_  8192
#define D_  512

// MFMA GEMM tiling
#define BM   128
#define NCT  8                 // col tiles of 64
#define NRT  (L_ / BM)         // 64
#define KW   64                // k bf16 per stage
#define NSTAGE (D_ / KW)       // 8
#define BUFW 8704              // 136 rows * 64 u16 per LDS buffer

// Scan chunking
#define CHUNK 64
#define NCHUNK (L_ / CHUNK)    // 128

#define MAXFIX 16380
#define FIX_TAU 1.0e-3f
#define FROWS 8                // rows per fixup tile
#define NSLICE 8               // col slices (64 cols each)

typedef short bf16x8 __attribute__((ext_vector_type(8)));
typedef float f32x4 __attribute__((ext_vector_type(4)));
typedef unsigned short u16;
typedef unsigned int u32;

// packed fp32x2 -> bf16x2 (hardware v_cvt_pk_bf16_f32, RNE)
__device__ __forceinline__ u32 pk2(float lo, float hi) {
    __hip_bfloat162 v = __float22bfloat162_rn(float2{lo, hi});
    union { __hip_bfloat162 b; u32 u; } cv; cv.b = v;
    return cv.u;
}

// async global->LDS, 16B per lane (dest = uniform base + lane*16)
#define GLOAD_LDS(g, l) __builtin_amdgcn_global_load_lds( \
    (__attribute__((address_space(1))) void*)(g),         \
    (__attribute__((address_space(3))) void*)(l), 16, 0, 0)

// ---------------------------------------------------------------------------
// prep_all: grid-split merge of h->bf16 conversion (blocks 0..NCONVB-1) and
// weight prep (bf16 copy + fp32 blocked transpose, last 64 blocks).
// ---------------------------------------------------------------------------
#define NCONVB ((B_ * L_ * D_) / (256 * 8))   // 8192 conv blocks

__global__ __launch_bounds__(256) void prep_all(
    const float* __restrict__ h, u16* __restrict__ h16,
    const float* __restrict__ wq, const float* __restrict__ wk,
    u16* __restrict__ qh, u16* __restrict__ kh,
    float* __restrict__ wqt, float* __restrict__ wkt,
    int* __restrict__ fix_cnt)
{
    __shared__ float tile[64][65];
    const int t = threadIdx.x;
    if (blockIdx.x < NCONVB) {
        size_t i = ((size_t)blockIdx.x * 256 + t) * 8;
        float4 a = *(const float4*)(h + i);
        float4 b = *(const float4*)(h + i + 4);
        uint4 v;
        v.x = pk2(a.x, a.y); v.y = pk2(a.z, a.w);
        v.z = pk2(b.x, b.y); v.w = pk2(b.z, b.w);
        *(uint4*)(h16 + i) = v;
        return;
    }
    const int wb = blockIdx.x - NCONVB;      // 0..63
    const int bi = wb & 7;                   // c tile
    const int bj = wb >> 3;                  // k tile
    if (wb == 0 && t == 0) *fix_cnt = 0;
    const int c0 = bi * 64, k0 = bj * 64;
    const float* src = wq; float* dst = wqt; u16* dsth = qh;
#pragma unroll
    for (int m = 0; m < 2; ++m) {
        __syncthreads();
#pragma unroll
        for (int it = 0; it < 4; ++it) {
            int r = it * 16 + (t >> 4);
            int cc = (t & 15) * 4;
            float4 v = *(const float4*)(src + (size_t)(c0 + r) * D_ + k0 + cc);
            tile[r][cc] = v.x; tile[r][cc + 1] = v.y;
            tile[r][cc + 2] = v.z; tile[r][cc + 3] = v.w;
            uint2 hv; hv.x = pk2(v.x, v.y); hv.y = pk2(v.z, v.w);
            *(uint2*)(dsth + (size_t)(c0 + r) * D_ + k0 + cc) = hv;
        }
        __syncthreads();
#pragma unroll
        for (int it = 0; it < 4; ++it) {
            int cl = t & 63;
            int kq = it * 4 + (t >> 6);
            float4 v;
            v.x = tile[cl][kq * 4 + 0]; v.y = tile[cl][kq * 4 + 1];
            v.z = tile[cl][kq * 4 + 2]; v.w = tile[cl][kq * 4 + 3];
            size_t o = ((size_t)((k0 >> 2) + kq) * 512 + (c0 + cl)) * 4;
            *(float4*)(dst + o) = v;
        }
        src = wk; dst = wkt; dsth = kh;
    }
}

// ---------------------------------------------------------------------------
// Shared-A bf16 MFMA kernel — 128x64 tile (NCT=8), gl_lds staging, 3-deep
// counted-vmcnt pipeline, red/ah LDS union (51 KB -> 3 blocks/CU):
//  - acc = 17 f32x4 (68 regs) -> register-unconstrained, 3 waves/SIMD
//  - stage: 4 gl_lds/wave (+1 edge on wave 0), issued 2 iterations ahead
//  - raw s_barrier + s_waitcnt vmcnt(4) (never 0 until last stage)
//  - order pinned: barrier -> B loads -> gl_lds S(s+2) -> MFMA
// part layout: [NCT][B][L][3]; arithmetic identical to verified r12.
// ---------------------------------------------------------------------------
__global__ __launch_bounds__(256, 2) void qk_mfma(
    const u16* __restrict__ h16,
    const u16* __restrict__ wqh, const u16* __restrict__ wkh,
    float* __restrict__ part)
{
    const int bid = blockIdx.x;
    const int swz = (bid & 7) * 256 + (bid >> 3);    // bijective, 2048%8==0
    const int ct = swz & 7, rt = (swz >> 3) & 63, b = swz >> 9;
    const int t = threadIdx.x, wid = t >> 6, lane = t & 63;
    const int l15 = lane & 15, l4 = lane >> 4;

    __shared__ __align__(16) union ShMem {
        u16 ah[3 * BUFW];              // 52224 B (loop)
        float red[4][BM][3];           // 6144 B (epilogue only)
    } sh;

    const int r0 = rt * BM;
    const u16* hb = h16 + (size_t)b * L_ * D_;

    // staging geometry: per-lane pre-swizzled global source, linear LDS dest
    const int rl0 = wid * 32 + (lane >> 3);
    const int csw = ((lane & 7) ^ ((lane >> 3) & 7)) * 8;
    const u16* gA = hb + (size_t)(r0 + rl0) * D_ + csw;
    const int dstw = wid * 32 * 64;
    // edge rows 128..135 (wave 0 only; rows 129+ garbage, provably unused)
    const u16* gE = hb + (size_t)(r0 + 128 + (lane >> 3)) * D_ + (lane & 7) * 8;

    // B-fragment pointers (16 cols per wave)
    const int colb = ct * 64 + wid * 16;
    const u16* bq0 = wqh + (size_t)(colb + l15) * D_ + l4 * 8;
    const u16* bk0 = wkh + (size_t)(colb + l15) * D_ + l4 * 8;

    // LDS read offsets (kk=0); kk=1 -> ^32 (chunk-XOR swizzle)
    int aoff[8];
#pragma unroll
    for (int rf = 0; rf < 8; ++rf) {
        int R = rf * 16 + l15;
        aoff[rf] = R * 64 + ((l4 ^ (R & 7)) * 8);
    }
    const int aoffE = 128 * 64 + l4 * 8;             // row 128 (unswizzled)

    f32x4 accq[8], acck[8], ackl;
    const f32x4 zero = {0.f, 0.f, 0.f, 0.f};
#pragma unroll
    for (int rf = 0; rf < 8; ++rf) { accq[rf] = zero; acck[rf] = zero; }
    ackl = zero;

#define STAGE_ISSUE(S, BUF) do { const size_t _o = (size_t)(S) * KW;  \
    u16* _d = &sh.ah[(BUF) * BUFW];                                   \
    GLOAD_LDS(gA + _o,         _d + dstw);                            \
    GLOAD_LDS(gA + _o + 4096,  _d + dstw + 512);                      \
    GLOAD_LDS(gA + _o + 8192,  _d + dstw + 1024);                     \
    GLOAD_LDS(gA + _o + 12288, _d + dstw + 1536);                     \
    if (wid == 0) GLOAD_LDS(gE + _o, _d + 8192); } while (0)

    // prologue: two stages in flight
    STAGE_ISSUE(0, 0);
    STAGE_ISSUE(1, 1);

    for (int s = 0; s < NSTAGE; ++s) {
        // drain S(s) only; S(s+1) stays in flight across the barrier
        if (s < NSTAGE - 1) {
            asm volatile("s_waitcnt vmcnt(4)" ::: "memory");
        } else {
            asm volatile("s_waitcnt vmcnt(0)" ::: "memory");
        }
        __builtin_amdgcn_sched_barrier(0);
        __builtin_amdgcn_s_barrier();
        __builtin_amdgcn_sched_barrier(0);

        // B fragments FIRST (so their consume-wait is counted, not a drain)
        const int so = s * KW;
        bf16x8 q00 = *(const bf16x8*)(bq0 + so);
        bf16x8 q01 = *(const bf16x8*)(bq0 + so + 32);
        bf16x8 k00 = *(const bf16x8*)(bk0 + so);
        bf16x8 k01 = *(const bf16x8*)(bk0 + so + 32);
        __builtin_amdgcn_sched_barrier(0);

        // prefetch S(s+2) — buf read at iter s-1 is free (all waves past the
        // barrier => done reading it). Stays in flight 2 iterations.
        if (s + 2 < NSTAGE) STAGE_ISSUE(s + 2, (s + 2) % 3);
        __builtin_amdgcn_sched_barrier(0);

        const u16* ab = &sh.ah[(s % 3) * BUFW];
#pragma unroll
        for (int kk = 0; kk < 2; ++kk) {
            bf16x8 fq = kk ? q01 : q00;
            bf16x8 fk = kk ? k01 : k00;
#pragma unroll
            for (int rf = 0; rf < 8; ++rf) {
                bf16x8 a = *(const bf16x8*)(ab + (aoff[rf] ^ (kk * 32)));
                accq[rf] = __builtin_amdgcn_mfma_f32_16x16x32_bf16(a, fq, accq[rf], 0, 0, 0);
                acck[rf] = __builtin_amdgcn_mfma_f32_16x16x32_bf16(a, fk, acck[rf], 0, 0, 0);
            }
            bf16x8 al = *(const bf16x8*)(ab + (aoffE ^ (kk * 32)));
            ackl = __builtin_amdgcn_mfma_f32_16x16x32_bf16(al, fk, ackl, 0, 0, 0);
        }
    }
#undef STAGE_ISSUE

    __syncthreads();   // ah -> red transition (union)

    // epilogue: per-row partials. C/D layout: col=lane&15, row=(lane>>4)*4+reg.
#pragma unroll
    for (int rf = 0; rf < 8; ++rf) {
#pragma unroll
        for (int reg = 0; reg < 4; ++reg) {
            float qv = accq[rf][reg];
            float kv = acck[rf][reg];
            float pq = qv * qv;
            float pk = kv * kv;
            float ksh;
            if (reg < 3) {
                ksh = acck[rf][reg + 1];
            } else {
                float up = __shfl(acck[rf][0], (lane + 16) & 63);
                float nx0 = (rf < 7) ? acck[rf + 1][0] : ackl[0];
                float nx = __shfl(nx0, l15);
                ksh = (l4 == 3) ? nx : up;
            }
            float pd = qv * ksh;
#pragma unroll
            for (int off = 1; off < 16; off <<= 1) {
                pq += __shfl_xor(pq, off);
                pk += __shfl_xor(pk, off);
                pd += __shfl_xor(pd, off);
            }
            if (l15 == 0) {
                int row = rf * 16 + l4 * 4 + reg;
                sh.red[wid][row][0] = pq;
                sh.red[wid][row][1] = pk;
                sh.red[wid][row][2] = pd;
            }
        }
    }
    __syncthreads();
    if (t < BM) {
        float pq = sh.red[0][t][0] + sh.red[1][t][0] + sh.red[2][t][0] + sh.red[3][t][0];
        float pk = sh.red[0][t][1] + sh.red[1][t][1] + sh.red[2][t][1] + sh.red[3][t][1];
        float pd = sh.red[0][t][2] + sh.red[1][t][2] + sh.red[2][t][2] + sh.red[3][t][2];
        size_t o = (((size_t)ct * B_ + b) * L_ + (r0 + t)) * 3;
        part[o + 0] = pq; part[o + 1] = pk; part[o + 2] = pd;
    }
}

// ---------------------------------------------------------------------------
// reduce partials -> p (nk read shifted by one row); flag borderline rows
// ---------------------------------------------------------------------------
__global__ __launch_bounds__(256) void cos_reduce(
    const float* __restrict__ part, float* __restrict__ p,
    int* __restrict__ fix_cnt, int* __restrict__ fix_list)
{
    int idx = blockIdx.x * 256 + threadIdx.x;
    if (idx >= B_ * L_) return;
    int b = idx / L_;
    int tp = idx % L_;
    if (tp == 0) { p[idx] = 1.0f; return; }
    int l = tp - 1;
    float nq = 0.f, nk = 0.f, dt = 0.f;
#pragma unroll
    for (int ct = 0; ct < NCT; ++ct) {
        size_t o = (((size_t)ct * B_ + b) * L_ + l) * 3;
        nq += part[o + 0];
        dt += part[o + 2];
        nk += part[o + 4];        // part[...][l+1][1]
    }
    float qn = sqrtf(nq); if (qn < 1e-12f) qn = 1e-12f;
    float kn = sqrtf(nk); if (kn < 1e-12f) kn = 1e-12f;
    float cs = dt / (qn * kn);
    float pr = 0.5f * (1.0f - cs);
    pr = fminf(fmaxf(pr, 0.0f), 1.0f);
    p[idx] = pr;
    if (fabsf(cs) < FIX_TAU) {
        int slot = atomicAdd(fix_cnt, 1);
        if (slot < MAXFIX) fix_list[slot] = idx;
    }
}

// ---------------------------------------------------------------------------
// fp32 fixup: item = (tile of 8 rows) x (64-col slice cs of 8). (r12, verified)
// ---------------------------------------------------------------------------
__global__ __launch_bounds__(256) void fixup_main(
    const float* __restrict__ h,
    const float* __restrict__ wqt, const float* __restrict__ wkt,
    const int* __restrict__ fix_cnt, const int* __restrict__ fix_list,
    float* __restrict__ part_fix)
{
    __shared__ float hq[FROWS][D_];
    __shared__ float hk[FROWS][D_];
    __shared__ float red[FROWS][3][4];
    const int t = threadIdx.x, wid = t >> 6, lane = t & 63;
    const int col16 = lane & 15, kpart = lane >> 4;
    int n = *fix_cnt; if (n > MAXFIX) n = MAXFIX;
    const int ntiles = (n + FROWS - 1) / FROWS;
    const int nitems = ntiles * NSLICE;

    for (int item = blockIdx.x; item < nitems; item += gridDim.x) {
        const int tile = item >> 3;
        const int cs = item & 7;
        __syncthreads();
#pragma unroll
        for (int r = 0; r < FROWS; ++r) {
            int s = tile * FROWS + r;
            int idx = fix_list[s < n ? s : 0];
            int bb = idx >> 13;                  // L_ = 8192
            int tp = idx & (L_ - 1);             // >= 1 for flagged rows
            const float* hr = h + ((size_t)bb * L_ + (tp - 1)) * D_;
            ((float2*)hq[r])[t] = ((const float2*)hr)[t];
            ((float2*)hk[r])[t] = ((const float2*)(hr + D_))[t];
        }
        __syncthreads();

        const int c = cs * 64 + wid * 16 + col16;   // global column
        float qa0, qa1, qa2, qa3, qa4, qa5, qa6, qa7;
        float ka0, ka1, ka2, ka3, ka4, ka5, ka6, ka7;
        qa0=qa1=qa2=qa3=qa4=qa5=qa6=qa7=0.f;
        ka0=ka1=ka2=ka3=ka4=ka5=ka6=ka7=0.f;

        const int k0 = kpart * 32;                  // 32 kq per kpart
        float4 wv = *(const float4*)(wqt + ((size_t)k0 * 512 + c) * 4);
        float4 xv = *(const float4*)(wkt + ((size_t)k0 * 512 + c) * 4);
#pragma unroll 4
        for (int kq = k0; kq < k0 + 32; ++kq) {
            const int kn = (kq + 1 < k0 + 32) ? kq + 1 : kq;
            float4 wn = *(const float4*)(wqt + ((size_t)kn * 512 + c) * 4);
            float4 xn = *(const float4*)(wkt + ((size_t)kn * 512 + c) * 4);
#define FROW(R, QA, KA) { \
            float4 hv = *(const float4*)(&hq[R][kq * 4]); \
            float4 kv = *(const float4*)(&hk[R][kq * 4]); \
            QA += hv.x*wv.x + hv.y*wv.y + hv.z*wv.z + hv.w*wv.w; \
            KA += kv.x*xv.x + kv.y*xv.y + kv.z*xv.z + kv.w*xv.w; }
            FROW(0, qa0, ka0) FROW(1, qa1, ka1) FROW(2, qa2, ka2) FROW(3, qa3, ka3)
            FROW(4, qa4, ka4) FROW(5, qa5, ka5) FROW(6, qa6, ka6) FROW(7, qa7, ka7)
#undef FROW
            wv = wn; xv = xn;
        }

#define REDROW(R, QA, KA) { \
        float qf = QA; qf += __shfl_xor(qf, 16); qf += __shfl_xor(qf, 32); \
        float kf = KA; kf += __shfl_xor(kf, 16); kf += __shfl_xor(kf, 32); \
        float pq = qf * qf, pk = kf * kf, pd = qf * kf; \
        pq += __shfl_xor(pq, 1); pk += __shfl_xor(pk, 1); pd += __shfl_xor(pd, 1); \
        pq += __shfl_xor(pq, 2); pk += __shfl_xor(pk, 2); pd += __shfl_xor(pd, 2); \
        pq += __shfl_xor(pq, 4); pk += __shfl_xor(pk, 4); pd += __shfl_xor(pd, 4); \
        pq += __shfl_xor(pq, 8); pk += __shfl_xor(pk, 8); pd += __shfl_xor(pd, 8); \
        if (lane == 0) { red[R][0][wid] = pq; red[R][1][wid] = pk; red[R][2][wid] = pd; } }
        REDROW(0, qa0, ka0) REDROW(1, qa1, ka1) REDROW(2, qa2, ka2) REDROW(3, qa3, ka3)
        REDROW(4, qa4, ka4) REDROW(5, qa5, ka5) REDROW(6, qa6, ka6) REDROW(7, qa7, ka7)
#undef REDROW
        __syncthreads();
        if (t < FROWS) {
            int s = tile * FROWS + t;
            if (s < n) {
                float* pp = part_fix + ((size_t)s * NSLICE + cs) * 3;
                pp[0] = red[t][0][0] + red[t][0][1] + red[t][0][2] + red[t][0][3];
                pp[1] = red[t][1][0] + red[t][1][1] + red[t][1][2] + red[t][1][3];
                pp[2] = red[t][2][0] + red[t][2][1] + red[t][2][2] + red[t][2][3];
            }
        }
    }
}

__global__ __launch_bounds__(256) void fixup_final(
    const int* __restrict__ fix_cnt, const int* __restrict__ fix_list,
    const float* __restrict__ part_fix, float* __restrict__ p)
{
    int n = *fix_cnt; if (n > MAXFIX) n = MAXFIX;
    for (int s = blockIdx.x * 256 + threadIdx.x; s < n; s += gridDim.x * 256) {
        float nq = 0.f, nk = 0.f, dt = 0.f;
#pragma unroll
        for (int cs = 0; cs < NSLICE; ++cs) {
            const float* pp = part_fix + ((size_t)s * NSLICE + cs) * 3;
            nq += pp[0]; nk += pp[1]; dt += pp[2];
        }
        float qn = sqrtf(nq); if (qn < 1e-12f) qn = 1e-12f;
        float kn = sqrtf(nk); if (kn < 1e-12f) kn = 1e-12f;
        float cs2 = dt / (qn * kn);
        float pr = 0.5f * (1.0f - cs2);
        pr = fminf(fmaxf(pr, 0.0f), 1.0f);
        p[fix_list[s]] = pr;
    }
}

// ---------------------------------------------------------------------------
// EMA scan, float2 per thread, branchless
// ---------------------------------------------------------------------------
__global__ __launch_bounds__(256) void scan_a(
    const float* __restrict__ h, const float* __restrict__ p,
    float* __restrict__ Bc, float* __restrict__ Ac)
{
    const int t = threadIdx.x;
    const int c = blockIdx.x, b = blockIdx.y;
    const int l0 = c * CHUNK;
    const float* pb = p + (size_t)b * L_ + l0;
    const float2* hb = (const float2*)(h + ((size_t)b * L_ + l0) * D_) + t;

    float2 st = {0.f, 0.f};
    float ap = 1.f;
#pragma unroll 4
    for (int i = 0; i < CHUNK; ++i) {
        float pr = pb[i];
        float2 hv = hb[(size_t)i * 256];
        bool sel = pr > 0.5f;
        float a = sel ? 1.f - pr : 1.f;
        float g = sel ? pr : 0.f;
        st.x = a * st.x + g * hv.x;
        st.y = a * st.y + g * hv.y;
        ap *= a;
    }
    ((float2*)Bc)[((size_t)b * NCHUNK + c) * 256 + t] = st;
    if (t == 0) Ac[b * NCHUNK + c] = ap;
}

// chunk-aggregate scan, software-pipelined in groups of 4
__global__ __launch_bounds__(256) void scan_b(
    const float* __restrict__ Ac, const float* __restrict__ Bc,
    const float* __restrict__ det, float* __restrict__ carry)
{
    const int t = threadIdx.x;
    const int b = blockIdx.x;
    const float* acb = Ac + b * NCHUNK;
    const float2* bcb = (const float2*)Bc + (size_t)b * NCHUNK * 256 + t;
    float2* cb = (float2*)carry + (size_t)b * NCHUNK * 256 + t;
    float2 st = ((const float2*)det)[(size_t)b * 256 + t];

    float a0 = acb[0], a1 = acb[1], a2 = acb[2], a3 = acb[3];
    float2 b0 = bcb[0], b1 = bcb[256], b2 = bcb[512], b3 = bcb[768];
    for (int g = 0; g < NCHUNK / 4; ++g) {
        const int nc = (g + 1 < NCHUNK / 4) ? (g + 1) * 4 : g * 4;
        float an0 = acb[nc], an1 = acb[nc + 1], an2 = acb[nc + 2], an3 = acb[nc + 3];
        float2 bn0 = bcb[(size_t)nc * 256],        bn1 = bcb[(size_t)(nc + 1) * 256];
        float2 bn2 = bcb[(size_t)(nc + 2) * 256],  bn3 = bcb[(size_t)(nc + 3) * 256];
        const size_t c0 = (size_t)g * 4 * 256;
        cb[c0]       = st; st.x = a0 * st.x + b0.x; st.y = a0 * st.y + b0.y;
        cb[c0 + 256] = st; st.x = a1 * st.x + b1.x; st.y = a1 * st.y + b1.y;
        cb[c0 + 512] = st; st.x = a2 * st.x + b2.x; st.y = a2 * st.y + b2.y;
        cb[c0 + 768] = st; st.x = a3 * st.x + b3.x; st.y = a3 * st.y + b3.y;
        a0 = an0; a1 = an1; a2 = an2; a3 = an3;
        b0 = bn0; b1 = bn1; b2 = bn2; b3 = bn3;
    }
}

__global__ __launch_bounds__(256) void scan_c(
    const float* __restrict__ h, const float* __restrict__ p,
    const float* __restrict__ res, const float* __restrict__ carry,
    float* __restrict__ out)
{
    const int t = threadIdx.x;
    const int c = blockIdx.x, b = blockIdx.y;
    const int l0 = c * CHUNK;
    const float* pb = p + (size_t)b * L_ + l0;
    const size_t base = ((size_t)b * L_ + l0) * 256 + t;   // float2 units
    const float2* hb = (const float2*)h + base;
    const float2* rb = (const float2*)res + base;
    float2* ob = (float2*)out + base;

    float2 st = ((const float2*)carry)[((size_t)b * NCHUNK + c) * 256 + t];
#pragma unroll 4
    for (int i = 0; i < CHUNK; ++i) {
        float pr = pb[i];
        float2 hv = hb[(size_t)i * 256];
        float2 rv = rb[(size_t)i * 256];
        bool sel = pr > 0.5f;
        float a = sel ? 1.f - pr : 1.f;
        float g = sel ? pr : 0.f;
        st.x = a * st.x + g * hv.x;
        st.y = a * st.y + g * hv.y;
        float2 ov; ov.x = rv.x + st.x; ov.y = rv.y + st.y;
        ob[(size_t)i * 256] = ov;
    }
}

// ---------------------------------------------------------------------------
extern "C" void kernel_launch(void* const* d_in, const int* in_sizes, int n_in,
                              void* d_out, int out_size, void* d_ws, size_t ws_size,
                              hipStream_t stream)
{
    const float* h   = (const float*)d_in[0];
    const float* res = (const float*)d_in[1];
    const float* wq  = (const float*)d_in[2];
    const float* wk  = (const float*)d_in[3];
    const float* det = (const float*)d_in[4];
    float* out = (float*)d_out;

    // d_out doubles as scratch for h-bf16 (33.5 MB < 67 MB);
    // scan_c overwrites it with the real output at the end.
    u16* h16 = (u16*)d_out;

    // ws layout (floats)
    float* ws = (float*)d_ws;
    float* part  = ws;                                     // NCT*B*L*3 = 786432
    float* p     = part + (size_t)NCT * B_ * L_ * 3;       // 32768
    float* Ac    = p + (size_t)B_ * L_;                    // 512
    float* Bc    = Ac + (size_t)B_ * NCHUNK;               // 262144
    float* carry = Bc + (size_t)B_ * NCHUNK * D_;          // 262144
    int*  fix_cnt  = (int*)(carry + (size_t)B_ * NCHUNK * D_);
    int*  fix_list = fix_cnt + 4;                          // MAXFIX ints
    u16* wqh = (u16*)(fix_list + MAXFIX);                  // D*D u16 each
    u16* wkh = wqh + (size_t)D_ * D_;
    float* wqt = (float*)(wkh + (size_t)D_ * D_);          // D*D f32 each
    float* wkt = wqt + (size_t)D_ * D_;
    float* part_fix = wkt + (size_t)D_ * D_;               // MAXFIX*8*3 f32

    prep_all<<<NCONVB + 64, 256, 0, stream>>>(h, h16, wq, wk, wqh, wkh,
                                              wqt, wkt, fix_cnt);
    qk_mfma<<<NCT * NRT * B_, 256, 0, stream>>>(h16, wqh, wkh, part);
    cos_reduce<<<(B_ * L_ + 255) / 256, 256, 0, stream>>>(part, p, fix_cnt, fix_list);
    fixup_main<<<1024, 256, 0, stream>>>(h, wqt, wkt, fix_cnt, fix_list, part_fix);
    fixup_final<<<64, 256, 0, stream>>>(fix_cnt, fix_list, part_fix, p);
    scan_a<<<dim3(NCHUNK, B_), 256, 0, stream>>>(h, p, Bc, Ac);
    scan_b<<<B_, 256, 0, stream>>>(Ac, Bc, det, carry);
    scan_c<<<dim3(NCHUNK, B_), 256, 0, stream>>>(h, p, res, carry, out);
}

// Round 16
// 162.472 us; speedup vs baseline: 1.1154x; 1.1154x over previous
//
#include <hip/hip_runtime.h>
#include <hip/hip_bf16.h>
#include <math.h>

// Problem constants
#define B_  4
#define L_  8192
#define D_  512

// MFMA GEMM tiling (r14 verified config: 128x128 tile, 3-deep pipeline)
#define BM   128
#define NCT  4                 // col tiles of 128
#define NRT  (L_ / BM)         // 64
#define KW   64                // k bf16 per stage
#define NSTAGE (D_ / KW)       // 8
#define BUFW 8704              // 136 rows * 64 u16 per LDS buffer

// Scan chunking
#define CHUNK 64
#define NCHUNK (L_ / CHUNK)    // 128

#define MAXFIX 16380
#define FIX_TAU 1.0e-3f
#define FROWS 8                // rows per fixup tile
#define NSLICE 8               // col slices (64 cols each)

typedef short bf16x8 __attribute__((ext_vector_type(8)));
typedef float f32x4 __attribute__((ext_vector_type(4)));
typedef unsigned short u16;
typedef unsigned int u32;

// packed fp32x2 -> bf16x2 (hardware v_cvt_pk_bf16_f32, RNE)
__device__ __forceinline__ u32 pk2(float lo, float hi) {
    __hip_bfloat162 v = __float22bfloat162_rn(float2{lo, hi});
    union { __hip_bfloat162 b; u32 u; } cv; cv.b = v;
    return cv.u;
}

// async global->LDS, 16B per lane (dest = uniform base + lane*16)
#define GLOAD_LDS(g, l) __builtin_amdgcn_global_load_lds( \
    (__attribute__((address_space(1))) void*)(g),         \
    (__attribute__((address_space(3))) void*)(l), 16, 0, 0)

// ---------------------------------------------------------------------------
// prep_all: grid-split merge of h->bf16 conversion (blocks 0..NCONVB-1) and
// weight prep (bf16 copy + fp32 blocked transpose, last 64 blocks).
// ---------------------------------------------------------------------------
#define NCONVB ((B_ * L_ * D_) / (256 * 8))   // 8192 conv blocks

__global__ __launch_bounds__(256) void prep_all(
    const float* __restrict__ h, u16* __restrict__ h16,
    const float* __restrict__ wq, const float* __restrict__ wk,
    u16* __restrict__ qh, u16* __restrict__ kh,
    float* __restrict__ wqt, float* __restrict__ wkt,
    int* __restrict__ fix_cnt)
{
    __shared__ float tile[64][65];
    const int t = threadIdx.x;
    if (blockIdx.x < NCONVB) {
        size_t i = ((size_t)blockIdx.x * 256 + t) * 8;
        float4 a = *(const float4*)(h + i);
        float4 b = *(const float4*)(h + i + 4);
        uint4 v;
        v.x = pk2(a.x, a.y); v.y = pk2(a.z, a.w);
        v.z = pk2(b.x, b.y); v.w = pk2(b.z, b.w);
        *(uint4*)(h16 + i) = v;
        return;
    }
    const int wb = blockIdx.x - NCONVB;      // 0..63
    const int bi = wb & 7;                   // c tile
    const int bj = wb >> 3;                  // k tile
    if (wb == 0 && t == 0) *fix_cnt = 0;
    const int c0 = bi * 64, k0 = bj * 64;
    const float* src = wq; float* dst = wqt; u16* dsth = qh;
#pragma unroll
    for (int m = 0; m < 2; ++m) {
        __syncthreads();
#pragma unroll
        for (int it = 0; it < 4; ++it) {
            int r = it * 16 + (t >> 4);
            int cc = (t & 15) * 4;
            float4 v = *(const float4*)(src + (size_t)(c0 + r) * D_ + k0 + cc);
            tile[r][cc] = v.x; tile[r][cc + 1] = v.y;
            tile[r][cc + 2] = v.z; tile[r][cc + 3] = v.w;
            uint2 hv; hv.x = pk2(v.x, v.y); hv.y = pk2(v.z, v.w);
            *(uint2*)(dsth + (size_t)(c0 + r) * D_ + k0 + cc) = hv;
        }
        __syncthreads();
#pragma unroll
        for (int it = 0; it < 4; ++it) {
            int cl = t & 63;
            int kq = it * 4 + (t >> 6);
            float4 v;
            v.x = tile[cl][kq * 4 + 0]; v.y = tile[cl][kq * 4 + 1];
            v.z = tile[cl][kq * 4 + 2]; v.w = tile[cl][kq * 4 + 3];
            size_t o = ((size_t)((k0 >> 2) + kq) * 512 + (c0 + cl)) * 4;
            *(float4*)(dst + o) = v;
        }
        src = wk; dst = wkt; dsth = kh;
    }
}

// ---------------------------------------------------------------------------
// Shared-A bf16 MFMA kernel — r14 verified config (best measured: 63.5 us):
// 128x128 tile, gl_lds staging, 3-deep counted-vmcnt pipeline, + LDS union.
// part layout: [NCT][B][L][3]
// ---------------------------------------------------------------------------
__global__ __launch_bounds__(256, 2) void qk_mfma(
    const u16* __restrict__ h16,
    const u16* __restrict__ wqh, const u16* __restrict__ wkh,
    float* __restrict__ part)
{
    const int bid = blockIdx.x;
    const int swz = (bid & 7) * 128 + (bid >> 3);    // bijective, 1024%8==0
    const int ct = swz & 3, rt = (swz >> 2) & 63, b = swz >> 8;
    const int t = threadIdx.x, wid = t >> 6, lane = t & 63;
    const int l15 = lane & 15, l4 = lane >> 4;

    __shared__ __align__(16) union ShMem {
        u16 ah[3 * BUFW];              // 52224 B (loop)
        float red[4][BM][3];           // 6144 B (epilogue only)
    } sh;

    const int r0 = rt * BM;
    const u16* hb = h16 + (size_t)b * L_ * D_;

    // staging geometry: per-lane pre-swizzled global source, linear LDS dest
    const int rl0 = wid * 32 + (lane >> 3);
    const int csw = ((lane & 7) ^ ((lane >> 3) & 7)) * 8;
    const u16* gA = hb + (size_t)(r0 + rl0) * D_ + csw;
    const int dstw = wid * 32 * 64;
    // edge rows 128..135 (wave 0 only; rows 129+ garbage, provably unused)
    const u16* gE = hb + (size_t)(r0 + 128 + (lane >> 3)) * D_ + (lane & 7) * 8;

    // B-fragment pointers
    const int colb = ct * 128 + wid * 32;
    const u16* bq0 = wqh + (size_t)(colb + l15) * D_ + l4 * 8;
    const u16* bq1 = bq0 + (size_t)16 * D_;
    const u16* bk0 = wkh + (size_t)(colb + l15) * D_ + l4 * 8;
    const u16* bk1 = bk0 + (size_t)16 * D_;

    // LDS read offsets (kk=0); kk=1 -> ^32 (chunk-XOR swizzle)
    int aoff[8];
#pragma unroll
    for (int rf = 0; rf < 8; ++rf) {
        int R = rf * 16 + l15;
        aoff[rf] = R * 64 + ((l4 ^ (R & 7)) * 8);
    }
    const int aoffE = 128 * 64 + l4 * 8;             // row 128 (unswizzled)

    f32x4 accq[8][2], acck[8][2], ackl[2];
    const f32x4 zero = {0.f, 0.f, 0.f, 0.f};
#pragma unroll
    for (int rf = 0; rf < 8; ++rf) {
        accq[rf][0] = zero; accq[rf][1] = zero;
        acck[rf][0] = zero; acck[rf][1] = zero;
    }
    ackl[0] = zero; ackl[1] = zero;

#define STAGE_ISSUE(S, BUF) do { const size_t _o = (size_t)(S) * KW;  \
    u16* _d = &sh.ah[(BUF) * BUFW];                                   \
    GLOAD_LDS(gA + _o,         _d + dstw);                            \
    GLOAD_LDS(gA + _o + 4096,  _d + dstw + 512);                      \
    GLOAD_LDS(gA + _o + 8192,  _d + dstw + 1024);                     \
    GLOAD_LDS(gA + _o + 12288, _d + dstw + 1536);                     \
    if (wid == 0) GLOAD_LDS(gE + _o, _d + 8192); } while (0)

    // prologue: two stages in flight
    STAGE_ISSUE(0, 0);
    STAGE_ISSUE(1, 1);

    for (int s = 0; s < NSTAGE; ++s) {
        // drain S(s) only; S(s+1) stays in flight across the barrier
        if (s < NSTAGE - 1) {
            asm volatile("s_waitcnt vmcnt(4)" ::: "memory");
        } else {
            asm volatile("s_waitcnt vmcnt(0)" ::: "memory");
        }
        __builtin_amdgcn_sched_barrier(0);
        __builtin_amdgcn_s_barrier();
        __builtin_amdgcn_sched_barrier(0);

        // B fragments FIRST (so their consume-wait is counted, not a drain)
        const int so = s * KW;
        bf16x8 q00 = *(const bf16x8*)(bq0 + so);
        bf16x8 q01 = *(const bf16x8*)(bq0 + so + 32);
        bf16x8 q10 = *(const bf16x8*)(bq1 + so);
        bf16x8 q11 = *(const bf16x8*)(bq1 + so + 32);
        bf16x8 k00 = *(const bf16x8*)(bk0 + so);
        bf16x8 k01 = *(const bf16x8*)(bk0 + so + 32);
        bf16x8 k10 = *(const bf16x8*)(bk1 + so);
        bf16x8 k11 = *(const bf16x8*)(bk1 + so + 32);
        __builtin_amdgcn_sched_barrier(0);

        // prefetch S(s+2); stays in flight 2 iterations
        if (s + 2 < NSTAGE) STAGE_ISSUE(s + 2, (s + 2) % 3);
        __builtin_amdgcn_sched_barrier(0);

        const u16* ab = &sh.ah[(s % 3) * BUFW];
#pragma unroll
        for (int kk = 0; kk < 2; ++kk) {
            bf16x8 fq0 = kk ? q01 : q00;
            bf16x8 fq1 = kk ? q11 : q10;
            bf16x8 fk0 = kk ? k01 : k00;
            bf16x8 fk1 = kk ? k11 : k10;
#pragma unroll
            for (int rf = 0; rf < 8; ++rf) {
                bf16x8 a = *(const bf16x8*)(ab + (aoff[rf] ^ (kk * 32)));
                accq[rf][0] = __builtin_amdgcn_mfma_f32_16x16x32_bf16(a, fq0, accq[rf][0], 0, 0, 0);
                accq[rf][1] = __builtin_amdgcn_mfma_f32_16x16x32_bf16(a, fq1, accq[rf][1], 0, 0, 0);
                acck[rf][0] = __builtin_amdgcn_mfma_f32_16x16x32_bf16(a, fk0, acck[rf][0], 0, 0, 0);
                acck[rf][1] = __builtin_amdgcn_mfma_f32_16x16x32_bf16(a, fk1, acck[rf][1], 0, 0, 0);
            }
            bf16x8 al = *(const bf16x8*)(ab + (aoffE ^ (kk * 32)));
            ackl[0] = __builtin_amdgcn_mfma_f32_16x16x32_bf16(al, fk0, ackl[0], 0, 0, 0);
            ackl[1] = __builtin_amdgcn_mfma_f32_16x16x32_bf16(al, fk1, ackl[1], 0, 0, 0);
        }
    }
#undef STAGE_ISSUE

    __syncthreads();   // ah -> red transition (union)

    // epilogue: per-row partials. C/D layout: col=lane&15, row=(lane>>4)*4+reg.
#pragma unroll
    for (int rf = 0; rf < 8; ++rf) {
#pragma unroll
        for (int reg = 0; reg < 4; ++reg) {
            float pq = 0.f, pk = 0.f, pd = 0.f;
#pragma unroll
            for (int cf = 0; cf < 2; ++cf) {
                float qv = accq[rf][cf][reg];
                float kv = acck[rf][cf][reg];
                pq += qv * qv;
                pk += kv * kv;
                float ksh;
                if (reg < 3) {
                    ksh = acck[rf][cf][reg + 1];
                } else {
                    float up = __shfl(acck[rf][cf][0], (lane + 16) & 63);
                    float nx0 = (rf < 7) ? acck[rf + 1][cf][0] : ackl[cf][0];
                    float nx = __shfl(nx0, l15);
                    ksh = (l4 == 3) ? nx : up;
                }
                pd += qv * ksh;
            }
#pragma unroll
            for (int off = 1; off < 16; off <<= 1) {
                pq += __shfl_xor(pq, off);
                pk += __shfl_xor(pk, off);
                pd += __shfl_xor(pd, off);
            }
            if (l15 == 0) {
                int row = rf * 16 + l4 * 4 + reg;
                sh.red[wid][row][0] = pq;
                sh.red[wid][row][1] = pk;
                sh.red[wid][row][2] = pd;
            }
        }
    }
    __syncthreads();
    if (t < BM) {
        float pq = sh.red[0][t][0] + sh.red[1][t][0] + sh.red[2][t][0] + sh.red[3][t][0];
        float pk = sh.red[0][t][1] + sh.red[1][t][1] + sh.red[2][t][1] + sh.red[3][t][1];
        float pd = sh.red[0][t][2] + sh.red[1][t][2] + sh.red[2][t][2] + sh.red[3][t][2];
        size_t o = (((size_t)ct * B_ + b) * L_ + (r0 + t)) * 3;
        part[o + 0] = pq; part[o + 1] = pk; part[o + 2] = pd;
    }
}

// ---------------------------------------------------------------------------
// reduce partials -> p (nk read shifted by one row); flag borderline rows
// ---------------------------------------------------------------------------
__global__ __launch_bounds__(256) void cos_reduce(
    const float* __restrict__ part, float* __restrict__ p,
    int* __restrict__ fix_cnt, int* __restrict__ fix_list)
{
    int idx = blockIdx.x * 256 + threadIdx.x;
    if (idx >= B_ * L_) return;
    int b = idx / L_;
    int tp = idx % L_;
    if (tp == 0) { p[idx] = 1.0f; return; }
    int l = tp - 1;
    float nq = 0.f, nk = 0.f, dt = 0.f;
#pragma unroll
    for (int ct = 0; ct < NCT; ++ct) {
        size_t o = (((size_t)ct * B_ + b) * L_ + l) * 3;
        nq += part[o + 0];
        dt += part[o + 2];
        nk += part[o + 4];        // part[...][l+1][1]
    }
    float qn = sqrtf(nq); if (qn < 1e-12f) qn = 1e-12f;
    float kn = sqrtf(nk); if (kn < 1e-12f) kn = 1e-12f;
    float cs = dt / (qn * kn);
    float pr = 0.5f * (1.0f - cs);
    pr = fminf(fmaxf(pr, 0.0f), 1.0f);
    p[idx] = pr;
    if (fabsf(cs) < FIX_TAU) {
        int slot = atomicAdd(fix_cnt, 1);
        if (slot < MAXFIX) fix_list[slot] = idx;
    }
}

// ---------------------------------------------------------------------------
// fp32 fixup: item = (tile of 8 rows) x (64-col slice cs of 8). (verified)
// ---------------------------------------------------------------------------
__global__ __launch_bounds__(256) void fixup_main(
    const float* __restrict__ h,
    const float* __restrict__ wqt, const float* __restrict__ wkt,
    const int* __restrict__ fix_cnt, const int* __restrict__ fix_list,
    float* __restrict__ part_fix)
{
    __shared__ float hq[FROWS][D_];
    __shared__ float hk[FROWS][D_];
    __shared__ float red[FROWS][3][4];
    const int t = threadIdx.x, wid = t >> 6, lane = t & 63;
    const int col16 = lane & 15, kpart = lane >> 4;
    int n = *fix_cnt; if (n > MAXFIX) n = MAXFIX;
    const int ntiles = (n + FROWS - 1) / FROWS;
    const int nitems = ntiles * NSLICE;

    for (int item = blockIdx.x; item < nitems; item += gridDim.x) {
        const int tile = item >> 3;
        const int cs = item & 7;
        __syncthreads();
#pragma unroll
        for (int r = 0; r < FROWS; ++r) {
            int s = tile * FROWS + r;
            int idx = fix_list[s < n ? s : 0];
            int bb = idx >> 13;                  // L_ = 8192
            int tp = idx & (L_ - 1);             // >= 1 for flagged rows
            const float* hr = h + ((size_t)bb * L_ + (tp - 1)) * D_;
            ((float2*)hq[r])[t] = ((const float2*)hr)[t];
            ((float2*)hk[r])[t] = ((const float2*)(hr + D_))[t];
        }
        __syncthreads();

        const int c = cs * 64 + wid * 16 + col16;   // global column
        float qa0, qa1, qa2, qa3, qa4, qa5, qa6, qa7;
        float ka0, ka1, ka2, ka3, ka4, ka5, ka6, ka7;
        qa0=qa1=qa2=qa3=qa4=qa5=qa6=qa7=0.f;
        ka0=ka1=ka2=ka3=ka4=ka5=ka6=ka7=0.f;

        const int k0 = kpart * 32;                  // 32 kq per kpart
        float4 wv = *(const float4*)(wqt + ((size_t)k0 * 512 + c) * 4);
        float4 xv = *(const float4*)(wkt + ((size_t)k0 * 512 + c) * 4);
#pragma unroll 4
        for (int kq = k0; kq < k0 + 32; ++kq) {
            const int kn = (kq + 1 < k0 + 32) ? kq + 1 : kq;
            float4 wn = *(const float4*)(wqt + ((size_t)kn * 512 + c) * 4);
            float4 xn = *(const float4*)(wkt + ((size_t)kn * 512 + c) * 4);
#define FROW(R, QA, KA) { \
            float4 hv = *(const float4*)(&hq[R][kq * 4]); \
            float4 kv = *(const float4*)(&hk[R][kq * 4]); \
            QA += hv.x*wv.x + hv.y*wv.y + hv.z*wv.z + hv.w*wv.w; \
            KA += kv.x*xv.x + kv.y*xv.y + kv.z*xv.z + kv.w*xv.w; }
            FROW(0, qa0, ka0) FROW(1, qa1, ka1) FROW(2, qa2, ka2) FROW(3, qa3, ka3)
            FROW(4, qa4, ka4) FROW(5, qa5, ka5) FROW(6, qa6, ka6) FROW(7, qa7, ka7)
#undef FROW
            wv = wn; xv = xn;
        }

#define REDROW(R, QA, KA) { \
        float qf = QA; qf += __shfl_xor(qf, 16); qf += __shfl_xor(qf, 32); \
        float kf = KA; kf += __shfl_xor(kf, 16); kf += __shfl_xor(kf, 32); \
        float pq = qf * qf, pk = kf * kf, pd = qf * kf; \
        pq += __shfl_xor(pq, 1); pk += __shfl_xor(pk, 1); pd += __shfl_xor(pd, 1); \
        pq += __shfl_xor(pq, 2); pk += __shfl_xor(pk, 2); pd += __shfl_xor(pd, 2); \
        pq += __shfl_xor(pq, 4); pk += __shfl_xor(pk, 4); pd += __shfl_xor(pd, 4); \
        pq += __shfl_xor(pq, 8); pk += __shfl_xor(pk, 8); pd += __shfl_xor(pd, 8); \
        if (lane == 0) { red[R][0][wid] = pq; red[R][1][wid] = pk; red[R][2][wid] = pd; } }
        REDROW(0, qa0, ka0) REDROW(1, qa1, ka1) REDROW(2, qa2, ka2) REDROW(3, qa3, ka3)
        REDROW(4, qa4, ka4) REDROW(5, qa5, ka5) REDROW(6, qa6, ka6) REDROW(7, qa7, ka7)
#undef REDROW
        __syncthreads();
        if (t < FROWS) {
            int s = tile * FROWS + t;
            if (s < n) {
                float* pp = part_fix + ((size_t)s * NSLICE + cs) * 3;
                pp[0] = red[t][0][0] + red[t][0][1] + red[t][0][2] + red[t][0][3];
                pp[1] = red[t][1][0] + red[t][1][1] + red[t][1][2] + red[t][1][3];
                pp[2] = red[t][2][0] + red[t][2][1] + red[t][2][2] + red[t][2][3];
            }
        }
    }
}

__global__ __launch_bounds__(256) void fixup_final(
    const int* __restrict__ fix_cnt, const int* __restrict__ fix_list,
    const float* __restrict__ part_fix, float* __restrict__ p)
{
    int n = *fix_cnt; if (n > MAXFIX) n = MAXFIX;
    for (int s = blockIdx.x * 256 + threadIdx.x; s < n; s += gridDim.x * 256) {
        float nq = 0.f, nk = 0.f, dt = 0.f;
#pragma unroll
        for (int cs = 0; cs < NSLICE; ++cs) {
            const float* pp = part_fix + ((size_t)s * NSLICE + cs) * 3;
            nq += pp[0]; nk += pp[1]; dt += pp[2];
        }
        float qn = sqrtf(nq); if (qn < 1e-12f) qn = 1e-12f;
        float kn = sqrtf(nk); if (kn < 1e-12f) kn = 1e-12f;
        float cs2 = dt / (qn * kn);
        float pr = 0.5f * (1.0f - cs2);
        pr = fminf(fmaxf(pr, 0.0f), 1.0f);
        p[fix_list[s]] = pr;
    }
}

// ---------------------------------------------------------------------------
// EMA scan; h read as bf16 (h16) — halves h traffic. Error <= ~0.005 absmax.
// ---------------------------------------------------------------------------
__global__ __launch_bounds__(256) void scan_a(
    const u16* __restrict__ h16, const float* __restrict__ p,
    float* __restrict__ Bc, float* __restrict__ Ac)
{
    const int t = threadIdx.x;
    const int c = blockIdx.x, b = blockIdx.y;
    const int l0 = c * CHUNK;
    const float* pb = p + (size_t)b * L_ + l0;
    const u32* hb = (const u32*)(h16 + ((size_t)b * L_ + l0) * D_) + t;

    float2 st = {0.f, 0.f};
    float ap = 1.f;
#pragma unroll 4
    for (int i = 0; i < CHUNK; ++i) {
        float pr = pb[i];
        u32 u = hb[(size_t)i * 256];
        float hx = __uint_as_float(u << 16);
        float hy = __uint_as_float(u & 0xffff0000u);
        bool sel = pr > 0.5f;
        float a = sel ? 1.f - pr : 1.f;
        float g = sel ? pr : 0.f;
        st.x = a * st.x + g * hx;
        st.y = a * st.y + g * hy;
        ap *= a;
    }
    ((float2*)Bc)[((size_t)b * NCHUNK + c) * 256 + t] = st;
    if (t == 0) Ac[b * NCHUNK + c] = ap;
}

// chunk-aggregate scan, software-pipelined in groups of 4
__global__ __launch_bounds__(256) void scan_b(
    const float* __restrict__ Ac, const float* __restrict__ Bc,
    const float* __restrict__ det, float* __restrict__ carry)
{
    const int t = threadIdx.x;
    const int b = blockIdx.x;
    const float* acb = Ac + b * NCHUNK;
    const float2* bcb = (const float2*)Bc + (size_t)b * NCHUNK * 256 + t;
    float2* cb = (float2*)carry + (size_t)b * NCHUNK * 256 + t;
    float2 st = ((const float2*)det)[(size_t)b * 256 + t];

    float a0 = acb[0], a1 = acb[1], a2 = acb[2], a3 = acb[3];
    float2 b0 = bcb[0], b1 = bcb[256], b2 = bcb[512], b3 = bcb[768];
    for (int g = 0; g < NCHUNK / 4; ++g) {
        const int nc = (g + 1 < NCHUNK / 4) ? (g + 1) * 4 : g * 4;
        float an0 = acb[nc], an1 = acb[nc + 1], an2 = acb[nc + 2], an3 = acb[nc + 3];
        float2 bn0 = bcb[(size_t)nc * 256],        bn1 = bcb[(size_t)(nc + 1) * 256];
        float2 bn2 = bcb[(size_t)(nc + 2) * 256],  bn3 = bcb[(size_t)(nc + 3) * 256];
        const size_t c0 = (size_t)g * 4 * 256;
        cb[c0]       = st; st.x = a0 * st.x + b0.x; st.y = a0 * st.y + b0.y;
        cb[c0 + 256] = st; st.x = a1 * st.x + b1.x; st.y = a1 * st.y + b1.y;
        cb[c0 + 512] = st; st.x = a2 * st.x + b2.x; st.y = a2 * st.y + b2.y;
        cb[c0 + 768] = st; st.x = a3 * st.x + b3.x; st.y = a3 * st.y + b3.y;
        a0 = an0; a1 = an1; a2 = an2; a3 = an3;
        b0 = bn0; b1 = bn1; b2 = bn2; b3 = bn3;
    }
}

// scan_c reading bf16 h (only valid when h16 does NOT alias d_out)
__global__ __launch_bounds__(256) void scan_c16(
    const u16* __restrict__ h16, const float* __restrict__ p,
    const float* __restrict__ res, const float* __restrict__ carry,
    float* __restrict__ out)
{
    const int t = threadIdx.x;
    const int c = blockIdx.x, b = blockIdx.y;
    const int l0 = c * CHUNK;
    const float* pb = p + (size_t)b * L_ + l0;
    const size_t base = ((size_t)b * L_ + l0) * 256 + t;   // float2 units
    const u32* hb = (const u32*)(h16 + ((size_t)b * L_ + l0) * D_) + t;
    const float2* rb = (const float2*)res + base;
    float2* ob = (float2*)out + base;

    float2 st = ((const float2*)carry)[((size_t)b * NCHUNK + c) * 256 + t];
#pragma unroll 4
    for (int i = 0; i < CHUNK; ++i) {
        float pr = pb[i];
        u32 u = hb[(size_t)i * 256];
        float hx = __uint_as_float(u << 16);
        float hy = __uint_as_float(u & 0xffff0000u);
        float2 rv = rb[(size_t)i * 256];
        bool sel = pr > 0.5f;
        float a = sel ? 1.f - pr : 1.f;
        float g = sel ? pr : 0.f;
        st.x = a * st.x + g * hx;
        st.y = a * st.y + g * hy;
        float2 ov; ov.x = rv.x + st.x; ov.y = rv.y + st.y;
        ob[(size_t)i * 256] = ov;
    }
}

// fallback scan_c reading fp32 h (used when h16 lives in d_out)
__global__ __launch_bounds__(256) void scan_c32(
    const float* __restrict__ h, const float* __restrict__ p,
    const float* __restrict__ res, const float* __restrict__ carry,
    float* __restrict__ out)
{
    const int t = threadIdx.x;
    const int c = blockIdx.x, b = blockIdx.y;
    const int l0 = c * CHUNK;
    const float* pb = p + (size_t)b * L_ + l0;
    const size_t base = ((size_t)b * L_ + l0) * 256 + t;   // float2 units
    const float2* hb = (const float2*)h + base;
    const float2* rb = (const float2*)res + base;
    float2* ob = (float2*)out + base;

    float2 st = ((const float2*)carry)[((size_t)b * NCHUNK + c) * 256 + t];
#pragma unroll 4
    for (int i = 0; i < CHUNK; ++i) {
        float pr = pb[i];
        float2 hv = hb[(size_t)i * 256];
        float2 rv = rb[(size_t)i * 256];
        bool sel = pr > 0.5f;
        float a = sel ? 1.f - pr : 1.f;
        float g = sel ? pr : 0.f;
        st.x = a * st.x + g * hv.x;
        st.y = a * st.y + g * hv.y;
        float2 ov; ov.x = rv.x + st.x; ov.y = rv.y + st.y;
        ob[(size_t)i * 256] = ov;
    }
}

// ---------------------------------------------------------------------------
extern "C" void kernel_launch(void* const* d_in, const int* in_sizes, int n_in,
                              void* d_out, int out_size, void* d_ws, size_t ws_size,
                              hipStream_t stream)
{
    const float* h   = (const float*)d_in[0];
    const float* res = (const float*)d_in[1];
    const float* wq  = (const float*)d_in[2];
    const float* wk  = (const float*)d_in[3];
    const float* det = (const float*)d_in[4];
    float* out = (float*)d_out;

    // ws layout (floats)
    float* ws = (float*)d_ws;
    float* part  = ws;                                     // NCT*B*L*3 = 393216
    float* p     = part + (size_t)NCT * B_ * L_ * 3;       // 32768
    float* Ac    = p + (size_t)B_ * L_;                    // 512
    float* Bc    = Ac + (size_t)B_ * NCHUNK;               // 262144
    float* carry = Bc + (size_t)B_ * NCHUNK * D_;          // 262144
    int*  fix_cnt  = (int*)(carry + (size_t)B_ * NCHUNK * D_);
    int*  fix_list = fix_cnt + 4;                          // MAXFIX ints
    u16* wqh = (u16*)(fix_list + MAXFIX);                  // D*D u16 each
    u16* wkh = wqh + (size_t)D_ * D_;
    float* wqt = (float*)(wkh + (size_t)D_ * D_);          // D*D f32 each
    float* wkt = wqt + (size_t)D_ * D_;
    float* part_fix = wkt + (size_t)D_ * D_;               // MAXFIX*8*3 f32
    u16* h16ws = (u16*)(part_fix + (size_t)MAXFIX * NSLICE * 3);
    const size_t h16_elems = (size_t)B_ * L_ * D_;
    const size_t needed = (size_t)((char*)(h16ws + h16_elems) - (char*)d_ws);

    // h16 placement: ws if it fits (lets scan_c read bf16 h while writing
    // d_out); else d_out-as-scratch with fp32-h fallback in scan_c.
    const bool use16 = (ws_size >= needed);
    u16* h16 = use16 ? h16ws : (u16*)d_out;

    prep_all<<<NCONVB + 64, 256, 0, stream>>>(h, h16, wq, wk, wqh, wkh,
                                              wqt, wkt, fix_cnt);
    qk_mfma<<<NCT * NRT * B_, 256, 0, stream>>>(h16, wqh, wkh, part);
    cos_reduce<<<(B_ * L_ + 255) / 256, 256, 0, stream>>>(part, p, fix_cnt, fix_list);
    fixup_main<<<1024, 256, 0, stream>>>(h, wqt, wkt, fix_cnt, fix_list, part_fix);
    fixup_final<<<64, 256, 0, stream>>>(fix_cnt, fix_list, part_fix, p);
    scan_a<<<dim3(NCHUNK, B_), 256, 0, stream>>>(h16, p, Bc, Ac);
    scan_b<<<B_, 256, 0, stream>>>(Ac, Bc, det, carry);
    if (use16) {
        scan_c16<<<dim3(NCHUNK, B_), 256, 0, stream>>>(h16, p, res, carry, out);
    } else {
        scan_c32<<<dim3(NCHUNK, B_), 256, 0, stream>>>(h, p, res, carry, out);
    }
}